// Round 5
// baseline (247.258 us; speedup 1.0000x reference)
//
#include <hip/hip_runtime.h>

typedef float f32x4 __attribute__((ext_vector_type(4)));

#define BB 16
#define FF 256
#define TT 8192
#define F_CHUNK 8
#define ROWS (F_CHUNK + 2)
#define THREADS 256
#define TBLK (THREADS * 4)     // 1024 floats per tile along t
#define TILES (TT / TBLK)      // 8 tiles per block strip
#define LROW 1024              // LDS row: 4KB; 2 bufs x 10 rows = 81920B -> 2 blocks/CU

__device__ __forceinline__ void dma16(const float* g, float* l) {
    // async global->LDS DMA, 16B/lane; dest = wave-uniform base + lane*16
    __builtin_amdgcn_global_load_lds(
        (const __attribute__((address_space(1))) unsigned int*)g,
        (__attribute__((address_space(3))) unsigned int*)l,
        16, 0, 0);
}

__device__ __forceinline__ int sgn_bit(float x) {
    return (int)(__float_as_uint(x) >> 31);
}

// phase(x) = 0 for x>=0, pi for x<0 -> adj code a = s(next)-s(cur) in {-1,0,1}
// out[g,t] = (a[g-1,t]==+1 ? in[g-1,t] : 0)
//          + (a[g,t]==0 || (g==0 && a<0) || (g==FF-1 && a>0) ? in[g,t] : 0)
//          + (a[g+1,t]==-1 ? in[g+1,t] : 0)
__global__ __launch_bounds__(THREADS) void sst_kernel(const float* __restrict__ in,
                                                      float* __restrict__ out) {
    __shared__ float sm[2][ROWS][LROW];

    const int tid  = threadIdx.x;
    const int wid  = tid >> 6;
    const int tid4 = tid * 4;
    const int fs   = blockIdx.x * F_CHUNK;
    const int b    = blockIdx.y;

    const float* srcR = in  + (size_t)b * FF * TT;
    float*       dstR = out + (size_t)b * FF * TT;

    // in-row clamp for the next-element sign read; tid==255 gets garbage here and is
    // fixed by the boundary epilogue below.
    const int eidx = (tid4 + 4 > LROW - 1) ? (LROW - 1) : (tid4 + 4);

    // issue 10 DMAs (one per row, 4KB each) for tile tt into buffer bb_
#define STAGE(tt, bb_) do {                                                        \
        _Pragma("unroll")                                                          \
        for (int i_ = 0; i_ < ROWS; ++i_) {                                        \
            int f_ = fs - 1 + i_;                                                  \
            f_ = f_ < 0 ? 0 : (f_ > FF - 1 ? FF - 1 : f_);                         \
            dma16(srcR + (size_t)f_ * TT + (tt) * TBLK + tid4,                     \
                  &sm[bb_][i_][wid * 256]);                                        \
        }                                                                          \
    } while (0)

    // ---- prologue: tiles 0 and 1 in flight (20 DMAs) ----
    STAGE(0, 0);
    STAGE(1, 1);

    #pragma unroll
    for (int k = 0; k < TILES; ++k) {
        // ---- counted wait: tile k's DMAs complete; newer ops stay in flight ----
        // FIFO vmcnt (m135): outstanding newest = next-tile DMAs (10) + prev stores (8).
        if (k == 0)              asm volatile("s_waitcnt vmcnt(10)" ::: "memory");
        else if (k == TILES - 1) asm volatile("s_waitcnt vmcnt(16)" ::: "memory");
        else                     asm volatile("s_waitcnt vmcnt(18)" ::: "memory");
        __builtin_amdgcn_sched_barrier(0);
        __builtin_amdgcn_s_barrier();            // all waves' tile-k DMAs landed
        asm volatile("" ::: "memory");

        const int bb = k & 1;

        // ---- LDS -> regs: values + next-element sign carriers ----
        f32x4 v[ROWS];
        float ee[ROWS];
        #pragma unroll
        for (int i = 0; i < ROWS; ++i) {
            v[i]  = *reinterpret_cast<const f32x4*>(&sm[bb][i][tid4]);
            ee[i] = sm[bb][i][eidx];
        }
        asm volatile("s_waitcnt lgkmcnt(0)" ::: "memory");  // reads done before buffer reuse
        __builtin_amdgcn_sched_barrier(0);
        __builtin_amdgcn_s_barrier();            // all waves done reading buf bb
        asm volatile("" ::: "memory");

        // ---- prefetch tile k+2 into the buffer we just freed ----
        if (k + 2 < TILES) STAGE(k + 2, bb);

        // ---- pack per-row adj codes (2-bit fields, bias +1); halo rows sentinel ----
        const bool tail = (k == TILES - 1) && (tid == THREADS - 1);
        unsigned pk[ROWS];
        #pragma unroll
        for (int i = 0; i < ROWS; ++i) {
            const int f = fs - 1 + i;
            const bool oob = (f < 0) | (f > FF - 1);
            const int s0 = sgn_bit(v[i][0]), s1 = sgn_bit(v[i][1]),
                      s2 = sgn_bit(v[i][2]), s3 = sgn_bit(v[i][3]), s4 = sgn_bit(ee[i]);
            const int a0 = s1 - s0 + 1;
            const int a1 = s2 - s1 + 1;
            const int a2 = s3 - s2 + 1;
            const int a3 = tail ? 1 : (s4 - s3 + 1);
            pk[i] = oob ? 0x55u : (unsigned)(a0 | (a1 << 2) | (a2 << 4) | (a3 << 6));
        }

        // ---- compute + store 8 output rows of this tile ----
        #pragma unroll
        for (int i = 1; i <= F_CHUNK; ++i) {
            const int g = fs + (i - 1);
            const bool isFirst = (g == 0);
            const bool isLast  = (g == FF - 1);

            const unsigned pp = pk[i - 1], pc = pk[i], pn = pk[i + 1];
            const f32x4    vp = v[i - 1],  vc = v[i],  vn = v[i + 1];

            f32x4 r;
            {
                const unsigned cp = pp & 3u, cc = pc & 3u, cn = pn & 3u;
                const bool bc = (cc == 1u) || (isFirst && cc == 0u) || (isLast && cc == 2u);
                r[0] = ((cp == 2u) ? vp[0] : 0.f) + (bc ? vc[0] : 0.f) + ((cn == 0u) ? vn[0] : 0.f);
            }
            {
                const unsigned cp = (pp >> 2) & 3u, cc = (pc >> 2) & 3u, cn = (pn >> 2) & 3u;
                const bool bc = (cc == 1u) || (isFirst && cc == 0u) || (isLast && cc == 2u);
                r[1] = ((cp == 2u) ? vp[1] : 0.f) + (bc ? vc[1] : 0.f) + ((cn == 0u) ? vn[1] : 0.f);
            }
            {
                const unsigned cp = (pp >> 4) & 3u, cc = (pc >> 4) & 3u, cn = (pn >> 4) & 3u;
                const bool bc = (cc == 1u) || (isFirst && cc == 0u) || (isLast && cc == 2u);
                r[2] = ((cp == 2u) ? vp[2] : 0.f) + (bc ? vc[2] : 0.f) + ((cn == 0u) ? vn[2] : 0.f);
            }
            {
                const unsigned cp = (pp >> 6) & 3u, cc = (pc >> 6) & 3u, cn = (pn >> 6) & 3u;
                const bool bc = (cc == 1u) || (isFirst && cc == 0u) || (isLast && cc == 2u);
                r[3] = ((cp == 2u) ? vp[3] : 0.f) + (bc ? vc[3] : 0.f) + ((cn == 0u) ? vn[3] : 0.f);
            }

            __builtin_nontemporal_store(
                r, reinterpret_cast<f32x4*>(dstR + (size_t)g * TT + k * TBLK + tid4));
        }
    }
#undef STAGE

    // ---- epilogue: fix the 7 tile-boundary columns (thread 255's w-lane used a
    // garbage next-sign in the main loop). 7 boundaries x 8 rows = 56 scalars. ----
    asm volatile("s_waitcnt vmcnt(0)" ::: "memory");  // main-loop stores retired
    __builtin_amdgcn_sched_barrier(0);
    __builtin_amdgcn_s_barrier();
    asm volatile("" ::: "memory");

    if (tid < (TILES - 1) * F_CHUNK) {
        const int kb = tid >> 3;                 // boundary index 0..6
        const int j  = tid & 7;                  // row-in-chunk 0..7
        const int g  = fs + j;
        const int c  = kb * TBLK + (TBLK - 1);   // global column 1023 + 1024*kb

        auto S = [&](int f, int cc) -> int {
            return sgn_bit(srcR[(size_t)f * TT + cc]);
        };
        const int am = (g - 1 >= 0)     ? (S(g - 1, c + 1) - S(g - 1, c)) : 9;
        const int ac =                     S(g,     c + 1) - S(g,     c);
        const int an = (g + 1 <= FF - 1) ? (S(g + 1, c + 1) - S(g + 1, c)) : 9;
        const bool bc = (ac == 0) || (g == 0 && ac < 0) || (g == FF - 1 && ac > 0);

        float r = 0.f;
        if (am == 1)  r += srcR[(size_t)(g - 1) * TT + c];
        if (bc)       r += srcR[(size_t)g * TT + c];
        if (an == -1) r += srcR[(size_t)(g + 1) * TT + c];
        dstR[(size_t)g * TT + c] = r;
    }
}

extern "C" void kernel_launch(void* const* d_in, const int* in_sizes, int n_in,
                              void* d_out, int out_size, void* d_ws, size_t ws_size,
                              hipStream_t stream) {
    const float* in  = (const float*)d_in[0];
    float*       out = (float*)d_out;
    // grid: (f-chunks, batch) = (32, 16) -> 512 persistent strips, exactly 2 blocks/CU
    dim3 grid(FF / F_CHUNK, BB);
    sst_kernel<<<grid, THREADS, 0, stream>>>(in, out);
}

// Round 7
// 228.579 us; speedup vs baseline: 1.0817x; 1.0817x over previous
//
#include <hip/hip_runtime.h>

typedef float f32x4 __attribute__((ext_vector_type(4)));

#define BB 16
#define FF 256
#define TT 8192
#define F_CHUNK 8
#define ROWS (F_CHUNK + 2)
#define THREADS 256
#define TBLK (THREADS * 4)   // 1024 floats per block along t
#define NXBLK (TT / TBLK)    // 8 t-blocks
#define LROW 1024            // 4KB LDS row; 10 rows = 40960B -> exactly 4 blocks/CU

__device__ __forceinline__ void dma16(const float* g, float* l) {
    // async global->LDS DMA, 16B/lane; dest = wave-uniform base + lane*16
    __builtin_amdgcn_global_load_lds(
        (const __attribute__((address_space(1))) unsigned int*)g,
        (__attribute__((address_space(3))) unsigned int*)l,
        16, 0, 0);
}

__device__ __forceinline__ int sgn_bit(float x) {
    return (int)(__float_as_uint(x) >> 31);
}

// phase(x) = 0 for x>=0, pi for x<0 -> adj code a = s(next)-s(cur) in {-1,0,1}
// out[g,t] = (a[g-1,t]==+1 ? in[g-1,t] : 0)
//          + (a[g,t]==0 || (g==0 && a<0) || (g==FF-1 && a>0) ? in[g,t] : 0)
//          + (a[g+1,t]==-1 ? in[g+1,t] : 0)
__global__ __launch_bounds__(THREADS) void sst_kernel(const float* __restrict__ in,
                                                      float* __restrict__ out) {
    __shared__ float sm[ROWS][LROW];

    const int tid    = threadIdx.x;
    const int wid    = tid >> 6;
    const int tid4   = tid * 4;
    const int blockT = blockIdx.x * TBLK;
    const int fs     = blockIdx.y * F_CHUNK;
    const int b      = blockIdx.z;

    const float* srcRow = in  + (size_t)b * FF * TT;
    float*       dstRow = out + (size_t)b * FF * TT;

    // ---- issue 10 DMAs in strict row order (FIFO vmcnt counting relies on it) ----
    #pragma unroll
    for (int i = 0; i < ROWS; ++i) {
        int f = fs - 1 + i;
        f = f < 0 ? 0 : (f > FF - 1 ? FF - 1 : f);   // halo clamped; pk sentinel neutralizes
        dma16(srcRow + (size_t)f * TT + blockT + tid4, &sm[i][wid * 256]);
        __builtin_amdgcn_sched_barrier(0);           // pin issue order
    }

    // in-row next-element index; thread 255 gets a garbage carrier -> fixed by patch
    const int  eidx    = (tid4 + 4 > LROW - 1) ? (LROW - 1) : (tid4 + 4);
    const bool tailThr = (blockIdx.x == NXBLK - 1) && (tid == THREADS - 1); // t = TT-1: adj 0

    f32x4    v[ROWS];
    unsigned pk[ROWS];

    auto finish_row = [&](int i) {
        v[i] = *reinterpret_cast<const f32x4*>(&sm[i][tid4]);
        const float e = sm[i][eidx];
        const int f   = fs - 1 + i;
        const bool oob = (f < 0) | (f > FF - 1);
        const int s0 = sgn_bit(v[i][0]), s1 = sgn_bit(v[i][1]),
                  s2 = sgn_bit(v[i][2]), s3 = sgn_bit(v[i][3]), s4 = sgn_bit(e);
        const int a0 = s1 - s0 + 1, a1 = s2 - s1 + 1, a2 = s3 - s2 + 1;
        const int a3 = tailThr ? 1 : (s4 - s3 + 1);
        pk[i] = oob ? 0x55u : (unsigned)(a0 | (a1 << 2) | (a2 << 4) | (a3 << 6));
    };

    auto emit_row = [&](int i) {   // output local row i -> global row fs + (i-1)
        const int g = fs + (i - 1);
        const bool isFirst = (g == 0), isLast = (g == FF - 1);
        const unsigned pp = pk[i - 1], pc = pk[i], pn = pk[i + 1];
        const f32x4    vp = v[i - 1],  vc = v[i],  vn = v[i + 1];
        f32x4 r;
        #pragma unroll
        for (int q = 0; q < 4; ++q) {
            const unsigned cp = (pp >> (2 * q)) & 3u;
            const unsigned cc = (pc >> (2 * q)) & 3u;
            const unsigned cn = (pn >> (2 * q)) & 3u;
            const bool bc = (cc == 1u) || (isFirst && cc == 0u) || (isLast && cc == 2u);
            r[q] = ((cp == 2u) ? vp[q] : 0.f) + (bc ? vc[q] : 0.f) + ((cn == 0u) ? vn[q] : 0.f);
        }
        __builtin_nontemporal_store(
            r, reinterpret_cast<f32x4*>(dstRow + (size_t)g * TT + blockT + tid4));
    };

    // ---- stage A: rows 0..3 ready -> outputs 1,2 ----
    // outstanding <= 6 => 4 oldest DMAs (rows 0-3) retired
    asm volatile("s_waitcnt vmcnt(6)" ::: "memory");
    __builtin_amdgcn_s_barrier();                    // cross-wave eidx visibility
    __builtin_amdgcn_sched_barrier(0);
    finish_row(0); finish_row(1); finish_row(2); finish_row(3);
    emit_row(1); emit_row(2);                        // stores S1,S2 join the vmcnt FIFO

    // ---- stage B: rows 4..6 -> outputs 3,4,5 ----
    // issued: 10 DMA + 2 stores; outstanding <= 5 (D7,D8,D9,S1,S2) => rows 0-6 retired
    asm volatile("s_waitcnt vmcnt(5)" ::: "memory");
    __builtin_amdgcn_s_barrier();
    __builtin_amdgcn_sched_barrier(0);
    finish_row(4); finish_row(5); finish_row(6);
    emit_row(3); emit_row(4); emit_row(5);           // S3,S4,S5

    // ---- stage C: rows 7..9 -> outputs 6,7,8 ----
    // issued: 10 DMA + 5 stores; outstanding <= 5 (S1..S5) => all DMAs retired
    asm volatile("s_waitcnt vmcnt(5)" ::: "memory");
    __builtin_amdgcn_s_barrier();
    __builtin_amdgcn_sched_barrier(0);
    finish_row(7); finish_row(8); finish_row(9);
    emit_row(6); emit_row(7); emit_row(8);

    // ---- patch epilogue: fix the tile-boundary column (thread 255's w-lane used a
    // garbage next-sign). 8 rows, 8 threads; only blocks that have a next tile. ----
    if (blockIdx.x != NXBLK - 1) {
        asm volatile("s_waitcnt vmcnt(0)" ::: "memory");  // main stores retired
        __builtin_amdgcn_s_barrier();
        __builtin_amdgcn_sched_barrier(0);
        if (tid < F_CHUNK) {
            const int g = fs + tid;
            const size_t cg = (size_t)(blockT + TBLK - 1);     // global col of last elem
            // values at column cg straight from LDS (rows tid, tid+1, tid+2)
            const float vpv = sm[tid][LROW - 1];
            const float vcv = sm[tid + 1][LROW - 1];
            const float vnv = sm[tid + 2][LROW - 1];
            // next-column signs from global (col cg+1 = next tile's first element)
            const float* nc = srcRow + cg + 1;
            const int am = (g - 1 >= 0)
                         ? (sgn_bit(nc[(size_t)(g - 1) * TT]) - sgn_bit(vpv)) : 9;
            const int ac =  sgn_bit(nc[(size_t)g * TT]) - sgn_bit(vcv);
            const int an = (g + 1 <= FF - 1)
                         ? (sgn_bit(nc[(size_t)(g + 1) * TT]) - sgn_bit(vnv)) : 9;
            const bool bcb = (ac == 0) || (g == 0 && ac < 0) || (g == FF - 1 && ac > 0);
            float r = 0.f;
            if (am == 1)  r += vpv;
            if (bcb)      r += vcv;
            if (an == -1) r += vnv;
            dstRow[(size_t)g * TT + cg] = r;
        }
    }
}

extern "C" void kernel_launch(void* const* d_in, const int* in_sizes, int n_in,
                              void* d_out, int out_size, void* d_ws, size_t ws_size,
                              hipStream_t stream) {
    const float* in  = (const float*)d_in[0];
    float*       out = (float*)d_out;
    // grid: (t-blocks, f-chunks, batch) = (8, 32, 16) -> 4096 one-shot blocks, 4/CU
    dim3 grid(NXBLK, FF / F_CHUNK, BB);
    sst_kernel<<<grid, THREADS, 0, stream>>>(in, out);
}